// Round 2
// baseline (1412.209 us; speedup 1.0000x reference)
//
#include <hip/hip_runtime.h>
#include <math.h>

// Problem constants (fixed by setup_inputs): B=8, N=131072, C=76
#define N_PER   131072
#define NBATCH  8
#define REGC    76
#define TOTAL   (NBATCH * N_PER)      // 1,048,576
#define TILE    2048                  // elements per radix block
#define NBLKSEG (N_PER / TILE)        // 64
#define BINS    256
#define SCTH    512                   // scatter threads
#define CHUNKS  (TILE / SCTH)         // 4
#define NG      (NBATCH * NBLKSEG)    // 512 blocks, seg = id&7 (XCD pin)
#define QROWS   (TOTAL / 4)           // 262144 decode rows per quarter

// ---------------------------------------------------------------------------
// key transform: float -> uint such that ascending uint sort == descending
// float sort; stable LSD radix preserves original index order on ties.
__device__ __forceinline__ unsigned desc_key(float f) {
    unsigned u = __float_as_uint(f);
    return (u & 0x80000000u) ? u : ~(u | 0x80000000u);
}

__device__ __forceinline__ unsigned wave_incl_scan(unsigned v, int lane) {
#pragma unroll
    for (int o = 1; o < 64; o <<= 1) {
        unsigned n = __shfl_up(v, o, 64);
        if (lane >= o) v += n;
    }
    return v;
}

// ---------------------------------------------------------------------------
// decode one proposal row (identical math to the verified round-1 kernel)
__device__ __forceinline__ void decode_one(
    int p, const float* __restrict__ scores, const float* __restrict__ reg,
    const float* __restrict__ xyz, float a0, float a1, float a2,
    float* __restrict__ boxes8)
{
    const float* r = reg + (size_t)p * REGC;          // row is 304B, 16B aligned
    const float4* r4 = (const float4*)r;

    float4 q0 = r4[0],  q1 = r4[1],  q2 = r4[2];      // x bins [0:12]
    float4 q3 = r4[3],  q4 = r4[4],  q5 = r4[5];      // z bins [12:24]
    float4 s0 = r4[12], s1 = r4[13], s2 = r4[14], s3 = r4[15]; // [48:64]
    float4 tt = r4[18];                                // [72:76]

    float xa[12] = {q0.x,q0.y,q0.z,q0.w, q1.x,q1.y,q1.z,q1.w, q2.x,q2.y,q2.z,q2.w};
    float za[12] = {q3.x,q3.y,q3.z,q3.w, q4.x,q4.y,q4.z,q4.w, q5.x,q5.y,q5.z,q5.w};
    float ra[12] = {s0.y,s0.z,s0.w, s1.x,s1.y,s1.z,s1.w, s2.x,s2.y,s2.z,s2.w, s3.x};

    int xb = 0; float xm = xa[0];
#pragma unroll
    for (int c = 1; c < 12; ++c) { if (xa[c] > xm) { xm = xa[c]; xb = c; } }
    int zb = 0; float zm = za[0];
#pragma unroll
    for (int c = 1; c < 12; ++c) { if (za[c] > zm) { zm = za[c]; zb = c; } }
    int yb = 0; float ym = ra[0];
#pragma unroll
    for (int c = 1; c < 12; ++c) { if (ra[c] > ym) { ym = ra[c]; yb = c; } }

    float x_res  = r[24 + xb];
    float z_res  = r[36 + zb];
    float ry_res = r[61 + yb];

    float rx  = xyz[(size_t)p * 3 + 0];
    float ryy = xyz[(size_t)p * 3 + 1];
    float rz  = xyz[(size_t)p * 3 + 2];

    const float APC    = (float)(2.0 * M_PI / 12.0);
    const float HAPC   = (float)(M_PI / 12.0);
    const float TWO_PI = (float)(2.0 * M_PI);
    const float PI_F   = (float)M_PI;

    float vry = __fadd_rn(__fmul_rn((float)yb, APC), __fmul_rn(ry_res, HAPC));
    float m = fmodf(vry, TWO_PI);
    if (m < 0.0f) m += TWO_PI;
    if (m > PI_F) m -= TWO_PI;

    float h = tt.y * a0 + a0;
    float w = tt.z * a1 + a1;
    float l = tt.w * a2 + a2;

    float ox = (((float)xb * 0.5f + 0.25f - 3.0f) + x_res * 0.5f) + rx;
    float oz = (((float)zb * 0.5f + 0.25f - 3.0f) + z_res * 0.5f) + rz;
    float oy = (ryy + s0.x) + h * 0.5f;   // post_process: y + h/2

    float sc = scores[p];

    float4* ob = (float4*)(boxes8 + (size_t)p * 8);
    ob[0] = make_float4(ox, oy, oz, h);
    ob[1] = make_float4(w, l, m, sc);
}

// ---------------------------------------------------------------------------
// Kernel 1: per-segment digit histograms for ALL FOUR passes in one read of
// scores (bin totals are pass-invariant wrt tile layout), fused with decode
// of quarter 0. ghist[seg][pass][bin] accumulated with global atomics.
__global__ __launch_bounds__(256) void hist_decode_kernel(
    const float* __restrict__ scores, const float* __restrict__ reg,
    const float* __restrict__ xyz, const float* __restrict__ anchor,
    float* __restrict__ boxes8, unsigned* __restrict__ ghist)
{
    __shared__ unsigned lh[4][BINS];
    int tid = threadIdx.x;
    lh[0][tid] = 0; lh[1][tid] = 0; lh[2][tid] = 0; lh[3][tid] = 0;
    __syncthreads();
    int id = blockIdx.x;                 // 0..511
    int seg = id & 7, blk = id >> 3;
    size_t base = (size_t)seg * N_PER + (size_t)blk * TILE;
#pragma unroll
    for (int c = 0; c < TILE / 256; ++c) {
        unsigned k = desc_key(scores[base + c * 256 + tid]);
        atomicAdd(&lh[0][k & 255u], 1u);
        atomicAdd(&lh[1][(k >> 8) & 255u], 1u);
        atomicAdd(&lh[2][(k >> 16) & 255u], 1u);
        atomicAdd(&lh[3][k >> 24], 1u);
    }
    __syncthreads();
#pragma unroll
    for (int p = 0; p < 4; ++p)
        atomicAdd(&ghist[(size_t)(seg * 4 + p) * BINS + tid], lh[p][tid]);

    // fused decode: quarter 0 (rows 0 .. QROWS-1), 2 rows per thread
    float a0 = anchor[0], a1 = anchor[1], a2 = anchor[2];
    int r0 = id * 512 + tid;
    decode_one(r0,       scores, reg, xyz, a0, a1, a2, boxes8);
    decode_one(r0 + 256, scores, reg, xyz, a0, a1, a2, boxes8);
}

// ---------------------------------------------------------------------------
// Scatter pass (onesweep): ballot-ranked stable scatter with decoupled
// lookback for cross-block prefixes (no hist kernel, no scan kernel).
// status word: [21:20]=flag(0 none,1 aggregate,2 inclusive) [19:18]=pass epoch
// [17:0]=count. One 512KB status buffer reused across passes via the epoch.
// PASS 0 derives keys from scores; PASS 1 carries top 16 bits; PASS 2 top 8;
// PASS 3 has fused gather (writes final output rows directly).
// PASS 0-2 carry a fused decode tail (quarters 1-3).
template<int PASS>
__global__ __launch_bounds__(SCTH) void scatter_kernel(
    const float* __restrict__ scores,
    const void* __restrict__ keyIn, const unsigned* __restrict__ payIn,
    void* __restrict__ keyOut, unsigned* __restrict__ payOut,
    const unsigned* __restrict__ ghist, unsigned* __restrict__ status,
    const float* __restrict__ reg, const float* __restrict__ xyz,
    const float* __restrict__ anchor, float* __restrict__ boxes8,
    float* __restrict__ out)
{
    __shared__ unsigned whist[CHUNKS * 8][BINS];          // 32 KB
    __shared__ unsigned skey[(PASS < 3) ? TILE : 1];      // 8 KB (not pass 3)
    __shared__ unsigned spay[TILE];                       // 8 KB
    __shared__ unsigned char sdig[TILE];                  // 2 KB
    __shared__ unsigned offs[BINS];                       // seg base + blk prefix
    __shared__ unsigned lexcl[BINS];                      // local digit base
    __shared__ unsigned wsum[4];

    const int tid  = threadIdx.x;
    const int wave = tid >> 6, lane = tid & 63;
    const unsigned long long lmask = (1ull << lane) - 1ull;
    const int id  = blockIdx.x;
    const int seg = id & 7, blk = id >> 3;                // XCD-pinned by segment
    const size_t segbase = (size_t)seg * N_PER;
    const int gbase = blk * TILE;

    // --- phase 1: segment bin bases from ghist; zero whist ------------------
    unsigned my_part = 0;
    if (tid < BINS) {
        unsigned tot = ghist[(size_t)(seg * 4 + PASS) * BINS + tid];
        unsigned v = wave_incl_scan(tot, lane);
        if (lane == 63) wsum[wave] = v;
        my_part = v - tot;
    } else {
        int z = tid - BINS;                               // 0..255
        unsigned* wf = &whist[0][0];
#pragma unroll
        for (int k = 0; k < CHUNKS * 8; ++k) wf[k * BINS + z] = 0;
    }
    __syncthreads();
    if (tid < BINS) {
        unsigned add = 0;
#pragma unroll
        for (int w2 = 0; w2 < 4; ++w2) { if (w2 < wave) add += wsum[w2]; }
        offs[tid] = my_part + add;                        // segment exclusive base
    }

    // --- phase 2: rank all chunks in parallel (elements in registers) -------
    unsigned kr[CHUNKS], pr[CHUNKS], dr[CHUNKS], rr[CHUNKS];
#pragma unroll
    for (int c = 0; c < CHUNKS; ++c) {
        int idx = c * SCTH + tid;
        unsigned outkey = 0, d, pay;
        if (PASS == 0) {
            unsigned k = desc_key(scores[segbase + gbase + idx]);
            outkey = k; d = k & 255u;
            pay = (unsigned)(gbase + idx);
        } else if (PASS == 1) {
            unsigned k = ((const unsigned*)keyIn)[segbase + gbase + idx];
            outkey = k >> 16; d = (k >> 8) & 255u;
            pay = payIn[segbase + gbase + idx];
        } else if (PASS == 2) {
            unsigned k = ((const unsigned short*)keyIn)[segbase + gbase + idx];
            outkey = k >> 8; d = k & 255u;
            pay = payIn[segbase + gbase + idx];
        } else {
            d = ((const unsigned char*)keyIn)[segbase + gbase + idx];
            pay = payIn[segbase + gbase + idx];
        }
        unsigned long long peers = ~0ull;
#pragma unroll
        for (int b = 0; b < 8; ++b) {
            unsigned long long vote = __ballot((d >> b) & 1u);
            peers &= ((d >> b) & 1u) ? vote : ~vote;
        }
        unsigned rank = (unsigned)__popcll(peers & lmask);
        if (rank == 0) whist[c * 8 + wave][d] = (unsigned)__popcll(peers);
        kr[c] = outkey; pr[c] = pay; dr[c] = d; rr[c] = rank;
    }
    __syncthreads();

    // --- phase 3: column prefix + decoupled lookback + local bases ----------
    unsigned my_lrun = 0, my_lpart = 0;
    if (tid < BINS) {
        unsigned run = 0;
#pragma unroll
        for (int i = 0; i < CHUNKS * 8; ++i) {
            unsigned v = whist[i][tid];
            whist[i][tid] = run;
            run += v;
        }
        my_lrun = run;                                    // block count for bin
        unsigned* stp = status + (size_t)(seg * NBLKSEG) * BINS + tid;
        unsigned pref = 0;
        if (blk == 0) {
            __hip_atomic_store(&stp[(size_t)blk * BINS],
                (2u << 20) | ((unsigned)PASS << 18) | run,
                __ATOMIC_RELEASE, __HIP_MEMORY_SCOPE_AGENT);
        } else {
            __hip_atomic_store(&stp[(size_t)blk * BINS],
                (1u << 20) | ((unsigned)PASS << 18) | run,
                __ATOMIC_RELEASE, __HIP_MEMORY_SCOPE_AGENT);
            int b = blk - 1;
            for (;;) {
                unsigned v;
                do {
                    v = __hip_atomic_load(&stp[(size_t)b * BINS],
                        __ATOMIC_ACQUIRE, __HIP_MEMORY_SCOPE_AGENT);
                } while (((v >> 18) & 3u) != (unsigned)PASS || (v >> 20) == 0u);
                pref += v & 0x3FFFFu;
                if ((v >> 20) == 2u) break;
                --b;
            }
            __hip_atomic_store(&stp[(size_t)blk * BINS],
                (2u << 20) | ((unsigned)PASS << 18) | (pref + run),
                __ATOMIC_RELEASE, __HIP_MEMORY_SCOPE_AGENT);
        }
        offs[tid] += pref;
        unsigned v2 = wave_incl_scan(run, lane);
        if (lane == 63) wsum[wave] = v2;
        my_lpart = v2 - run;
    }
    __syncthreads();
    if (tid < BINS) {
        unsigned add = 0;
#pragma unroll
        for (int w2 = 0; w2 < 4; ++w2) { if (w2 < wave) add += wsum[w2]; }
        lexcl[tid] = my_lpart + add;
    }
    __syncthreads();

    // --- phase 4: place into LDS at local sorted position -------------------
#pragma unroll
    for (int c = 0; c < CHUNKS; ++c) {
        unsigned j = lexcl[dr[c]] + whist[c * 8 + wave][dr[c]] + rr[c];
        if (PASS < 3) skey[j] = kr[c];
        spay[j] = pr[c];
        sdig[j] = (unsigned char)dr[c];
    }
    __syncthreads();

    // --- phase 5: coalesced write-out (pass 3: fused gather) ----------------
#pragma unroll
    for (int c = 0; c < CHUNKS; ++c) {
        unsigned j = (unsigned)(c * SCTH + tid);
        unsigned d = sdig[j];
        unsigned g = offs[d] + (j - lexcl[d]);
        unsigned pay = spay[j];
        if (PASS == 0) {
            ((unsigned*)keyOut)[segbase + g] = skey[j];
            payOut[segbase + g] = pay;
        } else if (PASS == 1) {
            ((unsigned short*)keyOut)[segbase + g] = (unsigned short)skey[j];
            payOut[segbase + g] = pay;
        } else if (PASS == 2) {
            ((unsigned char*)keyOut)[segbase + g] = (unsigned char)skey[j];
            payOut[segbase + g] = pay;
        } else {
            const float4* src = (const float4*)(boxes8 + (segbase + pay) * 8);
            float4 v0 = src[0], v1 = src[1];
            float4* dst = (float4*)(out + (segbase + g) * 8);
            dst[0] = v0; dst[1] = v1;
        }
    }

    // --- fused decode tail: quarter PASS+1 (passes 0-2 only) ----------------
    if constexpr (PASS < 3) {
        float a0 = anchor[0], a1 = anchor[1], a2 = anchor[2];
        int r = (PASS + 1) * QROWS + id * SCTH + tid;     // 1 row per thread
        decode_one(r, scores, reg, xyz, a0, a1, a2, boxes8);
    }
}

// ---------------------------------------------------------------------------
extern "C" void kernel_launch(void* const* d_in, const int* in_sizes, int n_in,
                              void* d_out, int out_size, void* d_ws, size_t ws_size,
                              hipStream_t stream)
{
    const float* scores = (const float*)d_in[0];
    const float* reg    = (const float*)d_in[1];
    const float* xyz    = (const float*)d_in[2];
    const float* anchor = (const float*)d_in[3];
    float* out = (float*)d_out;

    // workspace carve-up: 49,840,128 bytes (< previous 50,593,792)
    char* ws = (char*)d_ws;
    float*          boxes8 = (float*)ws;
    size_t off = (size_t)TOTAL * 8 * sizeof(float);                 // 33.55 MB
    unsigned*       keyB   = (unsigned*)(ws + off);       off += (size_t)TOTAL * 4;
    unsigned*       payB   = (unsigned*)(ws + off);       off += (size_t)TOTAL * 4;
    unsigned short* keyA16 = (unsigned short*)(ws + off); off += (size_t)TOTAL * 2;
    unsigned*       payA   = (unsigned*)(ws + off);       off += (size_t)TOTAL * 4;
    unsigned char*  keyC8  = (unsigned char*)(ws + off);  off += (size_t)TOTAL * 1;
    unsigned*       ghist  = (unsigned*)(ws + off);
    size_t ghist_bytes  = (size_t)NBATCH * 4 * BINS * 4;            // 32 KB
    off += ghist_bytes;
    unsigned*       status = (unsigned*)(ws + off);
    size_t status_bytes = (size_t)NBATCH * NBLKSEG * BINS * 4;      // 512 KB
    off += status_bytes;
    (void)ws_size; (void)in_sizes; (void)n_in; (void)out_size;

    // zero ghist + status (contiguous) once per launch
    hipMemsetAsync(ghist, 0, ghist_bytes + status_bytes, stream);

    // all-pass segment histograms + decode quarter 0
    hist_decode_kernel<<<NG, 256, 0, stream>>>(scores, reg, xyz, anchor,
                                               boxes8, ghist);

    // pass 0: scores -> keyB/payB (+ decode quarter 1)
    scatter_kernel<0><<<NG, SCTH, 0, stream>>>(scores, nullptr, nullptr,
        keyB, payB, ghist, status, reg, xyz, anchor, boxes8, nullptr);
    // pass 1: keyB/payB -> keyA16 (top 16 bits)/payA (+ decode quarter 2)
    scatter_kernel<1><<<NG, SCTH, 0, stream>>>(scores, keyB, payB,
        keyA16, payA, ghist, status, reg, xyz, anchor, boxes8, nullptr);
    // pass 2: keyA16/payA -> keyC8 (top 8 bits)/payB (+ decode quarter 3)
    scatter_kernel<2><<<NG, SCTH, 0, stream>>>(scores, keyA16, payA,
        keyC8, payB, ghist, status, reg, xyz, anchor, boxes8, nullptr);
    // pass 3: keyC8/payB -> fused gather, writes final output rows
    scatter_kernel<3><<<NG, SCTH, 0, stream>>>(nullptr, keyC8, payB,
        nullptr, nullptr, ghist, status, nullptr, nullptr, nullptr, boxes8, out);
}

// Round 3
// 522.845 us; speedup vs baseline: 2.7010x; 2.7010x over previous
//
#include <hip/hip_runtime.h>
#include <math.h>

// Problem constants (fixed by setup_inputs): B=8, N=131072, C=76
#define N_PER   131072
#define NBATCH  8
#define REGC    76
#define TOTAL   (NBATCH * N_PER)      // 1,048,576
#define TILE    2048                  // elements per radix block
#define NBLKSEG (N_PER / TILE)        // 64
#define BINS    256
#define SCTH    512                   // scatter threads
#define CHUNKS  (TILE / SCTH)         // 4
#define NG      (NBATCH * NBLKSEG)    // 512 blocks, seg = id&7 (XCD pin)
#define QROWS   (TOTAL / 4)           // 262144 decode rows per quarter

// ---------------------------------------------------------------------------
// key transform: float -> uint such that ascending uint sort == descending
// float sort; stable LSD radix preserves original index order on ties.
__device__ __forceinline__ unsigned desc_key(float f) {
    unsigned u = __float_as_uint(f);
    return (u & 0x80000000u) ? u : ~(u | 0x80000000u);
}

__device__ __forceinline__ unsigned wave_incl_scan(unsigned v, int lane) {
#pragma unroll
    for (int o = 1; o < 64; o <<= 1) {
        unsigned n = __shfl_up(v, o, 64);
        if (lane >= o) v += n;
    }
    return v;
}

// ---------------------------------------------------------------------------
// decode one proposal row (identical math to the verified round-1 kernel)
__device__ __forceinline__ void decode_one(
    int p, const float* __restrict__ scores, const float* __restrict__ reg,
    const float* __restrict__ xyz, float a0, float a1, float a2,
    float* __restrict__ boxes8)
{
    const float* r = reg + (size_t)p * REGC;          // row is 304B, 16B aligned
    const float4* r4 = (const float4*)r;

    float4 q0 = r4[0],  q1 = r4[1],  q2 = r4[2];      // x bins [0:12]
    float4 q3 = r4[3],  q4 = r4[4],  q5 = r4[5];      // z bins [12:24]
    float4 s0 = r4[12], s1 = r4[13], s2 = r4[14], s3 = r4[15]; // [48:64]
    float4 tt = r4[18];                                // [72:76]

    float xa[12] = {q0.x,q0.y,q0.z,q0.w, q1.x,q1.y,q1.z,q1.w, q2.x,q2.y,q2.z,q2.w};
    float za[12] = {q3.x,q3.y,q3.z,q3.w, q4.x,q4.y,q4.z,q4.w, q5.x,q5.y,q5.z,q5.w};
    float ra[12] = {s0.y,s0.z,s0.w, s1.x,s1.y,s1.z,s1.w, s2.x,s2.y,s2.z,s2.w, s3.x};

    int xb = 0; float xm = xa[0];
#pragma unroll
    for (int c = 1; c < 12; ++c) { if (xa[c] > xm) { xm = xa[c]; xb = c; } }
    int zb = 0; float zm = za[0];
#pragma unroll
    for (int c = 1; c < 12; ++c) { if (za[c] > zm) { zm = za[c]; zb = c; } }
    int yb = 0; float ym = ra[0];
#pragma unroll
    for (int c = 1; c < 12; ++c) { if (ra[c] > ym) { ym = ra[c]; yb = c; } }

    float x_res  = r[24 + xb];
    float z_res  = r[36 + zb];
    float ry_res = r[61 + yb];

    float rx  = xyz[(size_t)p * 3 + 0];
    float ryy = xyz[(size_t)p * 3 + 1];
    float rz  = xyz[(size_t)p * 3 + 2];

    const float APC    = (float)(2.0 * M_PI / 12.0);
    const float HAPC   = (float)(M_PI / 12.0);
    const float TWO_PI = (float)(2.0 * M_PI);
    const float PI_F   = (float)M_PI;

    float vry = __fadd_rn(__fmul_rn((float)yb, APC), __fmul_rn(ry_res, HAPC));
    float m = fmodf(vry, TWO_PI);
    if (m < 0.0f) m += TWO_PI;
    if (m > PI_F) m -= TWO_PI;

    float h = tt.y * a0 + a0;
    float w = tt.z * a1 + a1;
    float l = tt.w * a2 + a2;

    float ox = (((float)xb * 0.5f + 0.25f - 3.0f) + x_res * 0.5f) + rx;
    float oz = (((float)zb * 0.5f + 0.25f - 3.0f) + z_res * 0.5f) + rz;
    float oy = (ryy + s0.x) + h * 0.5f;   // post_process: y + h/2

    float sc = scores[p];

    float4* ob = (float4*)(boxes8 + (size_t)p * 8);
    ob[0] = make_float4(ox, oy, oz, h);
    ob[1] = make_float4(w, l, m, sc);
}

// ---------------------------------------------------------------------------
// Stage 2a: per-block digit histogram -> ushort hist[seg][blk][bin], fused
// with decode of quarter PASS (2 rows/thread). XCD-pinned: seg = blockIdx.x&7.
template<int PASS>
__global__ __launch_bounds__(256) void hist_kernel(
    const float* __restrict__ scores, const void* __restrict__ keyIn,
    unsigned short* __restrict__ hist,
    const float* __restrict__ reg, const float* __restrict__ xyz,
    const float* __restrict__ anchor, float* __restrict__ boxes8)
{
    __shared__ unsigned h[BINS];
    int tid = threadIdx.x;
    h[tid] = 0;
    __syncthreads();
    int id = blockIdx.x;
    int seg = id & 7, blk = id >> 3;
    size_t base = (size_t)seg * N_PER + (size_t)blk * TILE;
#pragma unroll
    for (int c = 0; c < TILE / 256; ++c) {
        unsigned d;
        if (PASS == 0)      d = desc_key(scores[base + c * 256 + tid]) & 255u;
        else if (PASS == 1) d = (((const unsigned*)keyIn)[base + c * 256 + tid] >> 8) & 255u;
        else if (PASS == 2) d = ((const unsigned short*)keyIn)[base + c * 256 + tid] & 255u;
        else                d = ((const unsigned char*)keyIn)[base + c * 256 + tid];
        atomicAdd(&h[d], 1u);
    }
    __syncthreads();
    hist[(size_t)(seg * NBLKSEG + blk) * BINS + tid] = (unsigned short)h[tid];

    // fused decode: quarter PASS (HBM streaming overlaps the L2-bound hist)
    float a0 = anchor[0], a1 = anchor[1], a2 = anchor[2];
    int r0 = PASS * QROWS + id * 512 + tid;
    decode_one(r0,       scores, reg, xyz, a0, a1, a2, boxes8);
    decode_one(r0 + 256, scores, reg, xyz, a0, a1, a2, boxes8);
}

// ---------------------------------------------------------------------------
// Stage 2b: stable scatter with self-service offsets (verified round-1
// scheme): each block reads its segment's per-block hist (L2-hot, 64x512B
// coalesced) and computes base[bin] + prefix-over-earlier-blocks locally.
// All CHUNKS ranked in parallel with elements in registers (ballot match),
// one column-prefix pass, LDS-staged placement, coalesced write-out.
// Narrow keys: PASS0 out 32b, PASS1 out top-16b, PASS2 out top-8b.
// PASS3: fused gather — writes final 32B output rows directly.
template<int PASS>
__global__ __launch_bounds__(SCTH) void scatter_kernel(
    const float* __restrict__ scores,
    const void* __restrict__ keyIn, const unsigned* __restrict__ payIn,
    void* __restrict__ keyOut, unsigned* __restrict__ payOut,
    const unsigned short* __restrict__ hist,
    const float* __restrict__ boxes8, float* __restrict__ out)
{
    __shared__ unsigned whist[CHUNKS * 8][BINS];          // 32 KB
    __shared__ unsigned skey[(PASS < 3) ? TILE : 1];      // 8 KB (not pass 3)
    __shared__ unsigned spay[TILE];                       // 8 KB
    __shared__ unsigned char sdig[TILE];                  // 2 KB
    __shared__ unsigned offs[BINS];                       // global pos of blk's 1st elem of bin
    __shared__ unsigned lexcl[BINS];                      // local digit base in [0,TILE)
    __shared__ unsigned wsum[4];

    const int tid  = threadIdx.x;
    const int wave = tid >> 6, lane = tid & 63;
    const unsigned long long lmask = (1ull << lane) - 1ull;
    const int id  = blockIdx.x;
    const int seg = id & 7, blk = id >> 3;                // XCD-pinned by segment
    const size_t segbase = (size_t)seg * N_PER;
    const int gbase = blk * TILE;

    // --- startup: self-service hist read (tid<256) / zero whist (tid>=256) --
    unsigned my_pref = 0, my_tot = 0;
    if (tid < BINS) {
        const unsigned short* hp = hist + (size_t)(seg * NBLKSEG) * BINS + tid;
        unsigned pref = 0, tot = 0;
#pragma unroll
        for (int b = 0; b < NBLKSEG; ++b) {
            unsigned c = hp[(size_t)b * BINS];
            tot += c;
            if (b < blk) pref += c;
        }
        my_pref = pref; my_tot = tot;
    } else {
        int z = tid - BINS;                               // 0..255
        unsigned* wf = &whist[0][0];
#pragma unroll
        for (int k = 0; k < CHUNKS * 8; ++k) wf[k * BINS + z] = 0;
    }
    __syncthreads();

    // exclusive scan of bin totals -> segment base
    unsigned my_base = 0;
    if (tid < BINS) {
        unsigned v = wave_incl_scan(my_tot, lane);
        if (lane == 63) wsum[wave] = v;
        my_base = v - my_tot;
    }
    __syncthreads();
    if (tid < BINS) {
        unsigned add = 0;
#pragma unroll
        for (int w2 = 0; w2 < 4; ++w2) { if (w2 < wave) add += wsum[w2]; }
        offs[tid] = my_base + add + my_pref;
    }

    // --- rank all chunks in parallel (elements live in registers) -----------
    unsigned kr[CHUNKS], pr[CHUNKS], dr[CHUNKS], rr[CHUNKS];
#pragma unroll
    for (int c = 0; c < CHUNKS; ++c) {
        int idx = c * SCTH + tid;
        unsigned outkey = 0, d, pay;
        if (PASS == 0) {
            unsigned k = desc_key(scores[segbase + gbase + idx]);
            outkey = k; d = k & 255u;
            pay = (unsigned)(gbase + idx);
        } else if (PASS == 1) {
            unsigned k = ((const unsigned*)keyIn)[segbase + gbase + idx];
            outkey = k >> 16; d = (k >> 8) & 255u;
            pay = payIn[segbase + gbase + idx];
        } else if (PASS == 2) {
            unsigned k = ((const unsigned short*)keyIn)[segbase + gbase + idx];
            outkey = k >> 8; d = k & 255u;
            pay = payIn[segbase + gbase + idx];
        } else {
            d = ((const unsigned char*)keyIn)[segbase + gbase + idx];
            pay = payIn[segbase + gbase + idx];
        }
        unsigned long long peers = ~0ull;
#pragma unroll
        for (int b = 0; b < 8; ++b) {
            unsigned long long vote = __ballot((d >> b) & 1u);
            peers &= ((d >> b) & 1u) ? vote : ~vote;
        }
        unsigned rank = (unsigned)__popcll(peers & lmask);
        if (rank == 0) whist[c * 8 + wave][d] = (unsigned)__popcll(peers);
        kr[c] = outkey; pr[c] = pay; dr[c] = d; rr[c] = rank;
    }
    __syncthreads();

    // --- column prefix over (chunk,wave) + local digit bases -----------------
    unsigned my_lrun = 0, my_lpart = 0;
    if (tid < BINS) {
        unsigned run = 0;
#pragma unroll
        for (int i = 0; i < CHUNKS * 8; ++i) {
            unsigned v = whist[i][tid];
            whist[i][tid] = run;
            run += v;
        }
        my_lrun = run;
        unsigned v = wave_incl_scan(run, lane);
        if (lane == 63) wsum[wave] = v;
        my_lpart = v - run;
    }
    __syncthreads();
    if (tid < BINS) {
        unsigned add = 0;
#pragma unroll
        for (int w2 = 0; w2 < 4; ++w2) { if (w2 < wave) add += wsum[w2]; }
        lexcl[tid] = my_lpart + add;
    }
    __syncthreads();

    // --- place into LDS at local sorted position -----------------------------
#pragma unroll
    for (int c = 0; c < CHUNKS; ++c) {
        unsigned j = lexcl[dr[c]] + whist[c * 8 + wave][dr[c]] + rr[c];
        if (PASS < 3) skey[j] = kr[c];
        spay[j] = pr[c];
        sdig[j] = (unsigned char)dr[c];
    }
    __syncthreads();

    // --- coalesced write-out (pass 3: fused gather to final output) ----------
#pragma unroll
    for (int c = 0; c < CHUNKS; ++c) {
        unsigned j = (unsigned)(c * SCTH + tid);
        unsigned d = sdig[j];
        unsigned g = offs[d] + (j - lexcl[d]);
        unsigned pay = spay[j];
        if (PASS == 0) {
            ((unsigned*)keyOut)[segbase + g] = skey[j];
            payOut[segbase + g] = pay;
        } else if (PASS == 1) {
            ((unsigned short*)keyOut)[segbase + g] = (unsigned short)skey[j];
            payOut[segbase + g] = pay;
        } else if (PASS == 2) {
            ((unsigned char*)keyOut)[segbase + g] = (unsigned char)skey[j];
            payOut[segbase + g] = pay;
        } else {
            const float4* src = (const float4*)(boxes8 + (segbase + pay) * 8);
            float4 v0 = src[0], v1 = src[1];
            float4* dst = (float4*)(out + (segbase + g) * 8);
            dst[0] = v0; dst[1] = v1;
        }
    }
}

// ---------------------------------------------------------------------------
extern "C" void kernel_launch(void* const* d_in, const int* in_sizes, int n_in,
                              void* d_out, int out_size, void* d_ws, size_t ws_size,
                              hipStream_t stream)
{
    const float* scores = (const float*)d_in[0];
    const float* reg    = (const float*)d_in[1];
    const float* xyz    = (const float*)d_in[2];
    const float* anchor = (const float*)d_in[3];
    float* out = (float*)d_out;

    // workspace carve-up: 48.8 MB (< 50.59 MB budget)
    char* ws = (char*)d_ws;
    float*          boxes8 = (float*)ws;
    size_t off = (size_t)TOTAL * 8 * sizeof(float);                 // 33.55 MB
    unsigned*       keyB   = (unsigned*)(ws + off);       off += (size_t)TOTAL * 4;
    unsigned*       payB   = (unsigned*)(ws + off);       off += (size_t)TOTAL * 4;
    unsigned short* keyA16 = (unsigned short*)(ws + off); off += (size_t)TOTAL * 2;
    unsigned*       payA   = (unsigned*)(ws + off);       off += (size_t)TOTAL * 4;
    unsigned char*  keyC8  = (unsigned char*)(ws + off);  off += (size_t)TOTAL * 1;
    unsigned short* hist   = (unsigned short*)(ws + off);
    off += (size_t)NBATCH * NBLKSEG * BINS * sizeof(unsigned short);  // 256 KB
    (void)ws_size; (void)in_sizes; (void)n_in; (void)out_size;

    // pass 0: scores -> keyB/payB (hist fused with decode quarter 0)
    hist_kernel<0><<<NG, 256, 0, stream>>>(scores, nullptr, hist,
                                           reg, xyz, anchor, boxes8);
    scatter_kernel<0><<<NG, SCTH, 0, stream>>>(scores, nullptr, nullptr,
        keyB, payB, hist, nullptr, nullptr);
    // pass 1: keyB/payB -> keyA16 (top 16 bits)/payA (+ decode quarter 1)
    hist_kernel<1><<<NG, 256, 0, stream>>>(scores, keyB, hist,
                                           reg, xyz, anchor, boxes8);
    scatter_kernel<1><<<NG, SCTH, 0, stream>>>(scores, keyB, payB,
        keyA16, payA, hist, nullptr, nullptr);
    // pass 2: keyA16/payA -> keyC8 (top 8 bits)/payB (+ decode quarter 2)
    hist_kernel<2><<<NG, 256, 0, stream>>>(scores, keyA16, hist,
                                           reg, xyz, anchor, boxes8);
    scatter_kernel<2><<<NG, SCTH, 0, stream>>>(scores, keyA16, payA,
        keyC8, payB, hist, nullptr, nullptr);
    // pass 3: keyC8/payB -> fused gather, writes final output (+ decode q3)
    hist_kernel<3><<<NG, 256, 0, stream>>>(scores, keyC8, hist,
                                           reg, xyz, anchor, boxes8);
    scatter_kernel<3><<<NG, SCTH, 0, stream>>>(scores, keyC8, payB,
        nullptr, nullptr, hist, boxes8, out);
}